// Round 4
// baseline (5083.121 us; speedup 1.0000x reference)
//
#include <hip/hip_runtime.h>
#include <math.h>

// Archetipes RNN scan: T=256 sequential steps, M=16 modules, H=256, I=128.
// R4: the step is a sync-latency chain (R3: VALUBusy 4.9%, HBM 0.6%,
// 13.7 us/step). Changes:
//  1. Two-level monotone barrier: 32 leaf counters (8 blocks each) + root.
//     Cuts same-LLC-line RMW serialization 256 -> 8+32. Relaxed polls +
//     ONE acquire fence (R3 polled with ACQUIRE = L1/L2 inv per poll).
//  2. Split-phase: arrive FIRST, then out[] stores + x[t+1] prefetch
//     overlap other blocks' arrivals, then wait.
// Weights stay register/AGPR-resident (R3: FETCH 2.53 GB -> 37 MB, one-time).
// Monotone epochs (E = leaf_v >> 3) survive graph replays with no resets.

#define DT_C    0.042f
#define GAMMA_C 2.7f
#define EPS_C   4.7f

constexpr int M = 16, H = 256, I = 128, T = 256;
constexpr int NROW = M * H;   // 4096
constexpr int NBLK = 256;
constexpr int NTHR = 1024;    // 16 waves

typedef float f32x4 __attribute__((ext_vector_type(4)));
typedef unsigned long long u64;

// ---- two-level monotone grid barrier (never reset; replay-safe) ----
__device__ unsigned int g_leaf[32];   // 8 blocks per leaf
__device__ unsigned int g_root;       // 32 adds per epoch

__device__ __forceinline__ unsigned int barrier_arrive(int bid) {
  // tid==0 only, after __syncthreads() (vmcnt drained per wave)
  unsigned int v = __hip_atomic_fetch_add(&g_leaf[bid >> 3], 1u,
                                          __ATOMIC_ACQ_REL, __HIP_MEMORY_SCOPE_AGENT);
  if ((v & 7u) == 7u)   // 8th arrival of this epoch in this group
    __hip_atomic_fetch_add(&g_root, 1u, __ATOMIC_RELEASE, __HIP_MEMORY_SCOPE_AGENT);
  return v >> 3;        // global epoch index (monotone across replays)
}
__device__ __forceinline__ void barrier_wait(unsigned int E) {
  const unsigned int target = (E + 1u) * 32u;
  while (__hip_atomic_load(&g_root, __ATOMIC_RELAXED,
                           __HIP_MEMORY_SCOPE_AGENT) < target)
    __builtin_amdgcn_s_sleep(1);
  __builtin_amdgcn_fence(__ATOMIC_ACQUIRE, "agent");
}

__global__ __launch_bounds__(NTHR) void rnn_persistent(
    const float* __restrict__ x,      // T*I
    const float* __restrict__ wm,     // M*M*H*H
    const float* __restrict__ conn,   // M*M
    const float* __restrict__ mask,   // M
    const float* __restrict__ W_in,   // M*H*I
    const float* __restrict__ W_rec,  // M*H*H
    const float* __restrict__ bias,   // M*H
    float* __restrict__ out,          // T*M*2*H state_seq, then T*M*H fb_seq
    float* hy_ws)                     // 2*NROW ping-pong
{
  const int h    = blockIdx.x;
  const int tid  = threadIdx.x;
  const int m    = tid >> 6;      // wave = module
  const int lane = tid & 63;

  __shared__ float hy_lds[NROW];        // 16 KB
  __shared__ float s_c[M * M];
  __shared__ float s_scal[M];
  __shared__ int   s_olist[M][M];
  __shared__ float s_oc[M][M];
  __shared__ int   s_ocnt[M];

  if (tid < M * M) s_c[tid] = conn[tid];
  __syncthreads();
  if (tid < M) {
    float s = 0.f; int cnt = 0;
    for (int o = 0; o < M; ++o) {
      float c = s_c[tid * M + o];
      s += c;
      if (c != 0.f) { s_olist[tid][cnt] = o; s_oc[tid][cnt] = c; ++cnt; }
    }
    for (int k = cnt; k < M; ++k) { s_olist[tid][k] = 0; s_oc[tid][k] = 0.f; }
    s_ocnt[tid] = cnt;
    s_scal[tid] = 1.0f / fmaxf(s, 1.0f);
  }
  __syncthreads();

  const int   row   = m * H + h;
  const float maskm = mask[m];
  const float biasv = bias[row];
  const float scal  = s_scal[m];
  const int   ocnt  = s_ocnt[m];

  // ---- one-time: weights into registers (conn pre-applied) ----
  f32x4 wreg[M];
#pragma unroll
  for (int k = 0; k < M; ++k) {
    if (k < ocnt) {
      const int o = s_olist[m][k];
      const f32x4 wv = *reinterpret_cast<const f32x4*>(
          wm + ((size_t)(m * M + o) * H + h) * H + 4 * lane);
      wreg[k] = wv * s_oc[m][k];
    } else {
      wreg[k] = (f32x4)0.f;
    }
  }
  const f32x4  wrec = *reinterpret_cast<const f32x4*>(W_rec + (size_t)row * H + 4 * lane);
  const float2 win  = *reinterpret_cast<const float2*>(W_in + (size_t)row * I + 2 * lane);

  // init hy buffer 0 (read at t=0); hz lives in lane0 register
  if (lane == 0)
    __hip_atomic_store(&hy_ws[row], 0.0f, __ATOMIC_RELAXED, __HIP_MEMORY_SCOPE_AGENT);
  float hz = 0.f;

  __syncthreads();
  if (tid == 0) { unsigned int E = barrier_arrive(h); barrier_wait(E); }
  __syncthreads();

  // x[0] prefetch (per-lane slice; same for every wave)
  float2 xd = *reinterpret_cast<const float2*>(x + 2 * lane);

  for (int t = 0; t < T; ++t) {
    const bool last = (t == T - 1);

    // stage hy_{t-1}: 16 B/thread via 2x agent-scope u64 loads -> LDS
    {
      const u64* src = reinterpret_cast<const u64*>(hy_ws + (size_t)(t & 1) * NROW) + 2 * tid;
      u64 a = __hip_atomic_load(src,     __ATOMIC_RELAXED, __HIP_MEMORY_SCOPE_AGENT);
      u64 b = __hip_atomic_load(src + 1, __ATOMIC_RELAXED, __HIP_MEMORY_SCOPE_AGENT);
      u64* dst = reinterpret_cast<u64*>(&hy_lds[4 * tid]);
      dst[0] = a; dst[1] = b;
    }
    __syncthreads();

    // input term (xd prefetched last iteration)
    float acc_o = win.x * (maskm * xd.x);
    acc_o = fmaf(win.y, maskm * xd.y, acc_o);
    // recurrent term
    {
      const f32x4 hp = *reinterpret_cast<const f32x4*>(&hy_lds[m * H + 4 * lane]);
      acc_o = fmaf(wrec.x, hp.x, acc_o);
      acc_o = fmaf(wrec.y, hp.y, acc_o);
      acc_o = fmaf(wrec.z, hp.z, acc_o);
      acc_o = fmaf(wrec.w, hp.w, acc_o);
    }
    // feedback: register weights x LDS hy fragments
    float acc_fb = 0.f;
#pragma unroll
    for (int k = 0; k < M; ++k) {
      if (k < ocnt) {
        const int o = s_olist[m][k];
        const f32x4 hp = *reinterpret_cast<const f32x4*>(&hy_lds[o * H + 4 * lane]);
        float po = wreg[k].x * hp.x;
        po = fmaf(wreg[k].y, hp.y, po);
        po = fmaf(wreg[k].z, hp.z, po);
        po = fmaf(wreg[k].w, hp.w, po);
        acc_fb += po;
      }
    }

    // wave-wide butterfly reduce
    for (int off = 32; off > 0; off >>= 1) {
      acc_fb += __shfl_xor(acc_fb, off);
      acc_o  += __shfl_xor(acc_o,  off);
    }

    float fb = 0.f, hy_n = 0.f, hz_n = 0.f;
    if (lane == 0) {
      fb = scal * acc_fb;
      const float hy_p = hy_lds[row];
      const float pre  = acc_o + biasv + fb;
      hz_n = hz + DT_C * (tanhf(pre) - GAMMA_C * hy_p - EPS_C * hz);
      hy_n = hy_p + DT_C * hz_n;
      hz = hz_n;
      // publish hy_t FIRST (the only value other blocks need)
      __hip_atomic_store(&hy_ws[(size_t)((t + 1) & 1) * NROW + row], hy_n,
                         __ATOMIC_RELAXED, __HIP_MEMORY_SCOPE_AGENT);
    }

    __syncthreads();   // all waves' hy stores vmcnt-drained -> safe to arrive

    unsigned int E = 0;
    if (tid == 0 && !last) E = barrier_arrive(h);

    // ---- overlap window: work no other block depends on ----
    if (lane == 0) {
      const size_t so = (size_t)t * (M * 2 * H) + (size_t)m * (2 * H);
      out[so + h]     = hy_n;
      out[so + H + h] = hz_n;
      out[(size_t)T * M * 2 * H + (size_t)t * (M * H) + row] = fb;
    }
    if (!last)
      xd = *reinterpret_cast<const float2*>(x + (size_t)(t + 1) * I + 2 * lane);

    if (tid == 0 && !last) barrier_wait(E);
    if (!last) __syncthreads();
  }
}

extern "C" void kernel_launch(void* const* d_in, const int* in_sizes, int n_in,
                              void* d_out, int out_size, void* d_ws, size_t ws_size,
                              hipStream_t stream) {
  const float* x     = (const float*)d_in[0];
  const float* wm    = (const float*)d_in[1];
  const float* conn  = (const float*)d_in[2];
  const float* mask  = (const float*)d_in[3];
  const float* W_in  = (const float*)d_in[4];
  const float* W_rec = (const float*)d_in[5];
  const float* bias  = (const float*)d_in[6];

  rnn_persistent<<<NBLK, NTHR, 0, stream>>>(
      x, wm, conn, mask, W_in, W_rec, bias,
      (float*)d_out, (float*)d_ws);
}

// Round 6
// 2661.662 us; speedup vs baseline: 1.9098x; 1.9098x over previous
//
#include <hip/hip_runtime.h>
#include <math.h>

// Archetipes RNN scan: T=256 sequential steps, M=16 modules, H=256, I=128.
// R6 = R5 flag structure + R3's proven coherent staging loads.
// R5 post-mortem (absmax 5.9e-3): two races from changing 2 things at once:
//   (a) consumer PLAIN float4 loads could hit stale remote-XCD L2 lines
//       (write-through agent stores do NOT invalidate remote L2 copies);
//   (b) RELAXED flag store could reach LLC before the data (different
//       LLC channels; no producer-side release ordering).
// Fixes: staging via agent-scope atomic u64 loads (LLC-direct, proven in
// R3/R4), flag stores are __ATOMIC_RELEASE (vmcnt already drained by
// __syncthreads, so release is ~free). Polls stay RELAXED: the
// __syncthreads between poll and staging orders them, and LLC-direct
// staging loads need no acquire invalidation.
//
// Sync design (no central barrier — R4 showed RMW chains/fences cost
// 0.25-1 us each on the critical path):
//   - g_hy[t][row]: dedicated slot per step, written once per launch.
//   - g_step[h]: per-producer monotone flag, ONE release store per step,
//     256 distinct addresses -> zero RMW serialization.
//   - base = own flag at entry; each launch adds exactly T to every flag
//     -> replay-safe (launches are stream-ordered, flags equal at entry).
// Weights register/AGPR-resident (R3: FETCH 2.53 GB -> 37 MB one-time).
// Work layout: block h <-> column h, wave w <-> module m (perfect balance).

#define DT_C    0.042f
#define GAMMA_C 2.7f
#define EPS_C   4.7f

constexpr int M = 16, H = 256, I = 128, T = 256;
constexpr int NROW = M * H;   // 4096
constexpr int NBLK = 256;
constexpr int NTHR = 1024;    // 16 waves

typedef float f32x4 __attribute__((ext_vector_type(4)));
typedef unsigned long long u64;

// Per-step hy slots (4 MB) + per-producer monotone flags. Persist across
// graph replays; flags only ever increase (+T per launch).
__device__ __align__(16) float g_hy[(size_t)T * NROW];
__device__ unsigned int g_step[NBLK];

__global__ __launch_bounds__(NTHR) void rnn_persistent(
    const float* __restrict__ x,      // T*I
    const float* __restrict__ wm,     // M*M*H*H
    const float* __restrict__ conn,   // M*M
    const float* __restrict__ mask,   // M
    const float* __restrict__ W_in,   // M*H*I
    const float* __restrict__ W_rec,  // M*H*H
    const float* __restrict__ bias,   // M*H
    float* __restrict__ out)          // T*M*2*H state_seq, then T*M*H fb_seq
{
  const int h    = blockIdx.x;
  const int tid  = threadIdx.x;
  const int m    = tid >> 6;      // wave = module
  const int lane = tid & 63;

  __shared__ float hy_lds[NROW];        // 16 KB
  __shared__ float s_c[M * M];
  __shared__ float s_scal[M];
  __shared__ int   s_olist[M][M];
  __shared__ float s_oc[M][M];
  __shared__ int   s_ocnt[M];
  __shared__ unsigned int s_base;

  if (tid == 0)
    s_base = __hip_atomic_load(&g_step[h], __ATOMIC_RELAXED, __HIP_MEMORY_SCOPE_AGENT);
  if (tid < M * M) s_c[tid] = conn[tid];
  __syncthreads();
  if (tid < M) {
    float s = 0.f; int cnt = 0;
    for (int o = 0; o < M; ++o) {
      float c = s_c[tid * M + o];
      s += c;
      if (c != 0.f) { s_olist[tid][cnt] = o; s_oc[tid][cnt] = c; ++cnt; }
    }
    for (int k = cnt; k < M; ++k) { s_olist[tid][k] = 0; s_oc[tid][k] = 0.f; }
    s_ocnt[tid] = cnt;
    s_scal[tid] = 1.0f / fmaxf(s, 1.0f);
  }
  __syncthreads();

  const int   row   = m * H + h;
  const float maskm = mask[m];
  const float biasv = bias[row];
  const float scal  = s_scal[m];
  const int   ocnt  = s_ocnt[m];
  const unsigned int base = s_base;

  // ---- one-time: weights into registers (conn pre-applied) ----
  f32x4 wreg[M];
#pragma unroll
  for (int k = 0; k < M; ++k) {
    if (k < ocnt) {
      const int o = s_olist[m][k];
      const f32x4 wv = *reinterpret_cast<const f32x4*>(
          wm + ((size_t)(m * M + o) * H + h) * H + 4 * lane);
      wreg[k] = wv * s_oc[m][k];
    } else {
      wreg[k] = (f32x4)0.f;
    }
  }
  const f32x4  wrec = *reinterpret_cast<const f32x4*>(W_rec + (size_t)row * H + 4 * lane);
  const float2 win  = *reinterpret_cast<const float2*>(W_in + (size_t)row * I + 2 * lane);

  // ---- publish #0: zeros into slot 0 (write-through agent stores) ----
  if (lane == 0)
    __hip_atomic_store(&g_hy[row], 0.0f, __ATOMIC_RELAXED, __HIP_MEMORY_SCOPE_AGENT);
  float hz = 0.f;
  __syncthreads();   // vmcnt(0): zero stores drained
  if (tid == 0)
    __hip_atomic_store(&g_step[h], base + 1u, __ATOMIC_RELEASE, __HIP_MEMORY_SCOPE_AGENT);

  // x[0] prefetch (per-lane slice; same for every wave)
  float2 xd = *reinterpret_cast<const float2*>(x + 2 * lane);

  for (int t = 0; t < T; ++t) {
    const bool last = (t == T - 1);

    // wait: publishes 0..t visible (256 flags polled in parallel, relaxed)
    if (tid < NBLK) {
      const unsigned int tgt = base + (unsigned int)t + 1u;
      while (__hip_atomic_load(&g_step[tid], __ATOMIC_RELAXED,
                               __HIP_MEMORY_SCOPE_AGENT) < tgt)
        __builtin_amdgcn_s_sleep(1);
    }
    __syncthreads();   // orders poll before staging for ALL threads

    // stage slot t -> LDS: 16 B/thread via 2x agent-scope u64 loads
    // (LLC-direct; immune to stale per-XCD L1/L2 lines)
    {
      const u64* src = reinterpret_cast<const u64*>(g_hy + (size_t)t * NROW) + 2 * tid;
      u64 a = __hip_atomic_load(src,     __ATOMIC_RELAXED, __HIP_MEMORY_SCOPE_AGENT);
      u64 b = __hip_atomic_load(src + 1, __ATOMIC_RELAXED, __HIP_MEMORY_SCOPE_AGENT);
      u64* dst = reinterpret_cast<u64*>(&hy_lds[4 * tid]);
      dst[0] = a; dst[1] = b;
    }
    __syncthreads();

    // input term (xd prefetched last iteration)
    float acc_o = win.x * (maskm * xd.x);
    acc_o = fmaf(win.y, maskm * xd.y, acc_o);
    // recurrent term
    {
      const f32x4 hp = *reinterpret_cast<const f32x4*>(&hy_lds[m * H + 4 * lane]);
      acc_o = fmaf(wrec.x, hp.x, acc_o);
      acc_o = fmaf(wrec.y, hp.y, acc_o);
      acc_o = fmaf(wrec.z, hp.z, acc_o);
      acc_o = fmaf(wrec.w, hp.w, acc_o);
    }
    // feedback: register weights x LDS hy fragments
    float acc_fb = 0.f;
#pragma unroll
    for (int k = 0; k < M; ++k) {
      if (k < ocnt) {
        const int o = s_olist[m][k];
        const f32x4 hp = *reinterpret_cast<const f32x4*>(&hy_lds[o * H + 4 * lane]);
        float po = wreg[k].x * hp.x;
        po = fmaf(wreg[k].y, hp.y, po);
        po = fmaf(wreg[k].z, hp.z, po);
        po = fmaf(wreg[k].w, hp.w, po);
        acc_fb += po;
      }
    }

    // wave-wide butterfly reduce
    for (int off = 32; off > 0; off >>= 1) {
      acc_fb += __shfl_xor(acc_fb, off);
      acc_o  += __shfl_xor(acc_o,  off);
    }

    float fb = 0.f, hy_n = 0.f, hz_n = 0.f;
    if (lane == 0) {
      fb = scal * acc_fb;
      const float hy_p = hy_lds[row];
      const float pre  = acc_o + biasv + fb;
      hz_n = hz + DT_C * (tanhf(pre) - GAMMA_C * hy_p - EPS_C * hz);
      hy_n = hy_p + DT_C * hz_n;
      hz = hz_n;
      // publish hy_t into slot t+1 (write-through, visible at LLC)
      if (!last)
        __hip_atomic_store(&g_hy[(size_t)(t + 1) * NROW + row], hy_n,
                           __ATOMIC_RELAXED, __HIP_MEMORY_SCOPE_AGENT);
    }

    __syncthreads();   // vmcnt(0) per wave: all 16 hy stores drained

    if (tid == 0 && !last)
      __hip_atomic_store(&g_step[h], base + (unsigned int)t + 2u,
                         __ATOMIC_RELEASE, __HIP_MEMORY_SCOPE_AGENT);

    // ---- overlap window: work no other block depends on ----
    if (lane == 0) {
      const size_t so = (size_t)t * (M * 2 * H) + (size_t)m * (2 * H);
      out[so + h]     = hy_n;
      out[so + H + h] = hz_n;
      out[(size_t)T * M * 2 * H + (size_t)t * (M * H) + row] = fb;
    }
    if (!last)
      xd = *reinterpret_cast<const float2*>(x + (size_t)(t + 1) * I + 2 * lane);
  }
}

extern "C" void kernel_launch(void* const* d_in, const int* in_sizes, int n_in,
                              void* d_out, int out_size, void* d_ws, size_t ws_size,
                              hipStream_t stream) {
  const float* x     = (const float*)d_in[0];
  const float* wm    = (const float*)d_in[1];
  const float* conn  = (const float*)d_in[2];
  const float* mask  = (const float*)d_in[3];
  const float* W_in  = (const float*)d_in[4];
  const float* W_rec = (const float*)d_in[5];
  const float* bias  = (const float*)d_in[6];

  rnn_persistent<<<NBLK, NTHR, 0, stream>>>(
      x, wm, conn, mask, W_in, W_rec, bias, (float*)d_out);
}

// Round 7
// 2264.900 us; speedup vs baseline: 2.2443x; 1.1752x over previous
//
#include <hip/hip_runtime.h>
#include <math.h>

// Archetipes RNN scan: T=256 sequential steps, M=16 modules, H=256, I=128.
// R7: strip the per-step critical path to its minimum.
// R6 post-mortem: 10.4 us/step, VALUBusy 6.9% (compute ~0.7 us), WRITE_SIZE
// 133 MB (10x the real 12.6 MB output) -> per-step scattered out[] stores'
// acks were drained by the mandatory vmcnt(0) before every __syncthreads.
// Changes:
//  1. out[] stores REMOVED from the loop: hz/fb buffered in LDS (2x16 KB),
//     hy published to g_hy slots 1..T anyway; single flush after the loop.
//  2. g_hy layout [t][h][m]: block h's 16 values = ONE 64-B line ->
//     publish drain waits on 1 line, not 16.
//  3. Fused poll+stage: thread tid polls only flag[tid>>2], then loads its
//     16 B and transposes into hy_lds[m][h] (4-way LDS conflict ~free per
//     m136). One fewer __syncthreads; straggler wait overlaps data staging.
// Sync invariants (validated R6): write-through agent data stores, drained
// by __syncthreads, then RELEASE flag store; relaxed polls + LLC-direct
// atomic staging loads (no acquire fences, no RMWs, 256 distinct flags).
// Monotone flags: +T per launch, base re-read at entry -> graph-replay safe.
// Weights register/AGPR-resident (R3: one-time 33.6 MB fetch).

#define DT_C    0.042f
#define GAMMA_C 2.7f
#define EPS_C   4.7f

constexpr int M = 16, H = 256, I = 128, T = 256;
constexpr int NROW = M * H;   // 4096
constexpr int NBLK = 256;
constexpr int NTHR = 1024;    // 16 waves

typedef float f32x4 __attribute__((ext_vector_type(4)));
typedef unsigned long long u64;

// Slot s (s=0..T) = hy after s steps, layout [s][h][m] (64 B per (s,h)).
// Written once per launch with bitwise-identical values -> replay-safe.
__device__ __align__(64) float g_hy[(size_t)(T + 1) * NROW];
__device__ unsigned int g_step[NBLK];   // per-producer monotone flags

__global__ __launch_bounds__(NTHR) void rnn_persistent(
    const float* __restrict__ x,      // T*I
    const float* __restrict__ wm,     // M*M*H*H
    const float* __restrict__ conn,   // M*M
    const float* __restrict__ mask,   // M
    const float* __restrict__ W_in,   // M*H*I
    const float* __restrict__ W_rec,  // M*H*H
    const float* __restrict__ bias,   // M*H
    float* __restrict__ out)          // T*M*2*H state_seq, then T*M*H fb_seq
{
  const int h    = blockIdx.x;
  const int tid  = threadIdx.x;
  const int m    = tid >> 6;      // wave = module
  const int lane = tid & 63;

  __shared__ float hy_lds[NROW];        // 16 KB, layout [m][h]
  __shared__ float outb_hz[T][M];       // 16 KB
  __shared__ float outb_fb[T][M];       // 16 KB
  __shared__ float s_c[M * M];
  __shared__ float s_scal[M];
  __shared__ int   s_olist[M][M];
  __shared__ float s_oc[M][M];
  __shared__ int   s_ocnt[M];
  __shared__ unsigned int s_base;

  if (tid == 0)
    s_base = __hip_atomic_load(&g_step[h], __ATOMIC_RELAXED, __HIP_MEMORY_SCOPE_AGENT);
  if (tid < M * M) s_c[tid] = conn[tid];
  __syncthreads();
  if (tid < M) {
    float s = 0.f; int cnt = 0;
    for (int o = 0; o < M; ++o) {
      float c = s_c[tid * M + o];
      s += c;
      if (c != 0.f) { s_olist[tid][cnt] = o; s_oc[tid][cnt] = c; ++cnt; }
    }
    for (int k = cnt; k < M; ++k) { s_olist[tid][k] = 0; s_oc[tid][k] = 0.f; }
    s_ocnt[tid] = cnt;
    s_scal[tid] = 1.0f / fmaxf(s, 1.0f);
  }
  __syncthreads();

  const int   row   = m * H + h;
  const float maskm = mask[m];
  const float biasv = bias[row];
  const float scal  = s_scal[m];
  const int   ocnt  = s_ocnt[m];
  const unsigned int base = s_base;

  // ---- one-time: weights into registers (conn pre-applied) ----
  f32x4 wreg[M];
#pragma unroll
  for (int k = 0; k < M; ++k) {
    if (k < ocnt) {
      const int o = s_olist[m][k];
      const f32x4 wv = *reinterpret_cast<const f32x4*>(
          wm + ((size_t)(m * M + o) * H + h) * H + 4 * lane);
      wreg[k] = wv * s_oc[m][k];
    } else {
      wreg[k] = (f32x4)0.f;
    }
  }
  const f32x4  wrec = *reinterpret_cast<const f32x4*>(W_rec + (size_t)row * H + 4 * lane);
  const float2 win  = *reinterpret_cast<const float2*>(W_in + (size_t)row * I + 2 * lane);

  // ---- publish slot 0 = zeros (one 64-B line per block) ----
  if (tid < M)
    __hip_atomic_store(&g_hy[(size_t)h * M + tid], 0.0f,
                       __ATOMIC_RELAXED, __HIP_MEMORY_SCOPE_AGENT);
  float hz = 0.f;
  __syncthreads();   // vmcnt(0): zero line drained
  if (tid == 0)
    __hip_atomic_store(&g_step[h], base + 1u, __ATOMIC_RELEASE, __HIP_MEMORY_SCOPE_AGENT);

  // x[0] prefetch (per-lane slice; same for every wave)
  float2 xd = *reinterpret_cast<const float2*>(x + 2 * lane);

  for (int t = 0; t < T; ++t) {
    const bool last = (t == T - 1);

    // ---- fused poll + stage: thread tid needs only column hcol ----
    {
      const int hcol = tid >> 2;            // source column / flag index
      const int moff = (tid & 3) * 4;       // my 4 modules of that column
      const unsigned int tgt = base + (unsigned int)t + 1u;
      while (__hip_atomic_load(&g_step[hcol], __ATOMIC_RELAXED,
                               __HIP_MEMORY_SCOPE_AGENT) < tgt)
        __builtin_amdgcn_s_sleep(1);
      const u64* src = reinterpret_cast<const u64*>(g_hy + (size_t)t * NROW) + 2 * tid;
      u64 a = __hip_atomic_load(src,     __ATOMIC_RELAXED, __HIP_MEMORY_SCOPE_AGENT);
      u64 b = __hip_atomic_load(src + 1, __ATOMIC_RELAXED, __HIP_MEMORY_SCOPE_AGENT);
      union { u64 q[2]; float f[4]; } u; u.q[0] = a; u.q[1] = b;
      hy_lds[(moff + 0) * H + hcol] = u.f[0];
      hy_lds[(moff + 1) * H + hcol] = u.f[1];
      hy_lds[(moff + 2) * H + hcol] = u.f[2];
      hy_lds[(moff + 3) * H + hcol] = u.f[3];
    }
    __syncthreads();

    // input term (xd prefetched last iteration)
    float acc_o = win.x * (maskm * xd.x);
    acc_o = fmaf(win.y, maskm * xd.y, acc_o);
    // recurrent term
    {
      const f32x4 hp = *reinterpret_cast<const f32x4*>(&hy_lds[m * H + 4 * lane]);
      acc_o = fmaf(wrec.x, hp.x, acc_o);
      acc_o = fmaf(wrec.y, hp.y, acc_o);
      acc_o = fmaf(wrec.z, hp.z, acc_o);
      acc_o = fmaf(wrec.w, hp.w, acc_o);
    }
    // feedback: register weights x LDS hy fragments
    float acc_fb = 0.f;
#pragma unroll
    for (int k = 0; k < M; ++k) {
      if (k < ocnt) {
        const int o = s_olist[m][k];
        const f32x4 hp = *reinterpret_cast<const f32x4*>(&hy_lds[o * H + 4 * lane]);
        float po = wreg[k].x * hp.x;
        po = fmaf(wreg[k].y, hp.y, po);
        po = fmaf(wreg[k].z, hp.z, po);
        po = fmaf(wreg[k].w, hp.w, po);
        acc_fb += po;
      }
    }

    // wave-wide butterfly reduce
    for (int off = 32; off > 0; off >>= 1) {
      acc_fb += __shfl_xor(acc_fb, off);
      acc_o  += __shfl_xor(acc_o,  off);
    }

    if (lane == 0) {
      const float fb   = scal * acc_fb;
      const float hy_p = hy_lds[row];
      const float pre  = acc_o + biasv + fb;
      const float hz_n = hz + DT_C * (tanhf(pre) - GAMMA_C * hy_p - EPS_C * hz);
      const float hy_n = hy_p + DT_C * hz_n;
      hz = hz_n;
      // publish hy_t into slot t+1: 16 waves' stores hit ONE 64-B line
      __hip_atomic_store(&g_hy[(size_t)(t + 1) * NROW + h * M + m], hy_n,
                         __ATOMIC_RELAXED, __HIP_MEMORY_SCOPE_AGENT);
      // buffer hz/fb in LDS; flushed once after the loop
      outb_hz[t][m] = hz_n;
      outb_fb[t][m] = fb;
    }

    __syncthreads();   // vmcnt(0): the single publish line drained

    if (tid == 0 && !last)
      __hip_atomic_store(&g_step[h], base + (unsigned int)t + 2u,
                         __ATOMIC_RELEASE, __HIP_MEMORY_SCOPE_AGENT);

    if (!last)
      xd = *reinterpret_cast<const float2*>(x + (size_t)(t + 1) * I + 2 * lane);
  }

  // ---- one-time flush: hy from own g_hy slots, hz/fb from LDS ----
  const size_t fb_base = (size_t)T * M * 2 * H;
  for (int i = tid; i < T * M; i += NTHR) {
    const int t  = i >> 4;
    const int mm = i & 15;
    const float hyv = __hip_atomic_load(&g_hy[(size_t)(t + 1) * NROW + h * M + mm],
                                        __ATOMIC_RELAXED, __HIP_MEMORY_SCOPE_AGENT);
    const size_t so = (size_t)t * (M * 2 * H) + (size_t)mm * (2 * H);
    out[so + h]     = hyv;
    out[so + H + h] = outb_hz[t][mm];
    out[fb_base + (size_t)t * (M * H) + (size_t)mm * H + h] = outb_fb[t][mm];
  }
}

extern "C" void kernel_launch(void* const* d_in, const int* in_sizes, int n_in,
                              void* d_out, int out_size, void* d_ws, size_t ws_size,
                              hipStream_t stream) {
  const float* x     = (const float*)d_in[0];
  const float* wm    = (const float*)d_in[1];
  const float* conn  = (const float*)d_in[2];
  const float* mask  = (const float*)d_in[3];
  const float* W_in  = (const float*)d_in[4];
  const float* W_rec = (const float*)d_in[5];
  const float* bias  = (const float*)d_in[6];

  rnn_persistent<<<NBLK, NTHR, 0, stream>>>(
      x, wm, conn, mask, W_in, W_rec, bias, (float*)d_out);
}